// Round 5
// baseline (608.214 us; speedup 1.0000x reference)
//
#include <hip/hip_runtime.h>
#include <cstdint>
#include <cstddef>

#define NN 8000
#define EE 64000
#define HH 10
#define WPB 4  // waves (edges) per k_edge3 block

// ---------------- ws layout (float offsets) ----------------
// deg      : 0          (NN)
// dout     : NN         (NN)      (init 1.0, accumulates outdeg -> outdeg+1)
// sum_in   : 2*NN       (64*NN)
// sum_src  : 66*NN      (64*NN)
// ea_sum   : 130*NN     (64*NN)
// eaQ      : 194*NN     (64*NN)   (= ea_sum @ Wek)
// eaK      : 258*NN     (64*NN)   (= ea_sum @ Weq)
// eaV      : 322*NN     (64*NN)   (= ea_sum @ Wev)
// xsrc     : 386*NN     (640*NN)
// NB       : 1026*NN    (640*NN)  (= node_update @ W4_bot)
// qk       : 1666*NN    (10*NN)
// sm       : 1676*NN    (10*NN)
// A        : 1686*NN    (64*EE)   (= edge_attr @ W4_top)
// Cg       : 1686*NN+64*EE  (64)  (= g1^T @ W5)
// Cb       : +64            (64)  (= b1^T @ W5)

__device__ __forceinline__ int rfl(int v) { return __builtin_amdgcn_readfirstlane(v); }

// ---------------------------------------------------------------------------
__global__ void k_init(float* __restrict__ ws) {
  int t = blockIdx.x * 256 + threadIdx.x;
  int stride = gridDim.x * 256;
  for (int i = t; i < 130 * NN; i += stride)
    ws[i] = (i >= NN && i < 2 * NN) ? 1.0f : 0.0f;
}

// ---------------------------------------------------------------------------
__global__ void k_scatter(const int* __restrict__ ei, const float* __restrict__ ea,
                          float* __restrict__ deg, float* __restrict__ dout,
                          float* __restrict__ sum_in, float* __restrict__ sum_src) {
  int t = blockIdx.x * 256 + threadIdx.x;
  if (t >= EE * 64) return;
  int e = t >> 6, f = t & 63;
  int s = ei[e];
  int d = ei[EE + e];
  float v = ea[t];
  atomicAdd(&sum_in[d * 64 + f], v);
  atomicAdd(&sum_src[s * 64 + f], v);
  if (f == 0) {
    atomicAdd(&deg[d], 1.0f);
    atomicAdd(&dout[s], 1.0f);
  }
}

// ---------------------------------------------------------------------------
__global__ void k_easum(const float* __restrict__ deg, const float* __restrict__ sum_in,
                        const float* __restrict__ sum_src, float* __restrict__ ea_sum) {
  int t = blockIdx.x * 256 + threadIdx.x;
  if (t >= NN * 64) return;
  int n = t >> 6;
  ea_sum[t] = sum_src[t] + sum_in[t] / fmaxf(deg[n], 1.0f);
}

// ---------------------------------------------------------------------------
// Cg[c] = sum_f g1[f]W5[f][c]; Cb[c] = sum_f b1[f]W5[f][c]
__global__ void k_prep(const float* __restrict__ W5, const float* __restrict__ g1,
                       const float* __restrict__ b1, float* __restrict__ Cg,
                       float* __restrict__ Cb) {
  int c = threadIdx.x;  // 64 threads
  float cg = 0.f, cb = 0.f;
  for (int f = 0; f < 64; ++f) {
    float w = W5[f * 64 + c];
    cg = fmaf(g1[f], w, cg);
    cb = fmaf(b1[f], w, cb);
  }
  Cg[c] = cg;
  Cb[c] = cb;
}

// ---------------------------------------------------------------------------
// Row template: out[r][c] = sum_f in[r][f] * W[f][c], weights-in-VGPR.
__global__ __launch_bounds__(256) void k_rowmm(const float* __restrict__ in,
                                               const float* __restrict__ W,
                                               float* __restrict__ out, int rows) {
  const int lane = threadIdx.x & 63;
  const int wv = rfl(threadIdx.x >> 6);
  float w[64];
#pragma unroll
  for (int f = 0; f < 64; ++f) w[f] = W[f * 64 + lane];
  const int nw = gridDim.x * 4;
  for (int r = blockIdx.x * 4 + wv; r < rows; r += nw) {
    const float* xr = in + (size_t)r * 64;
    float a0 = 0, a1 = 0, a2 = 0, a3 = 0;
#pragma unroll
    for (int f = 0; f < 64; f += 4) {
      a0 = fmaf(xr[f], w[f], a0);
      a1 = fmaf(xr[f + 1], w[f + 1], a1);
      a2 = fmaf(xr[f + 2], w[f + 2], a2);
      a3 = fmaf(xr[f + 3], w[f + 3], a3);
    }
    out[(size_t)r * 64 + lane] = (a0 + a1) + (a2 + a3);
  }
}

// ---------------------------------------------------------------------------
// xsrc[n, h*64+c] = sum_f x[n][f] * Wsrc[f][h*64+c]; gridDim.y = h
__global__ __launch_bounds__(256) void k_xsrc(const float* __restrict__ x,
                                              const float* __restrict__ Wsrc,
                                              float* __restrict__ xsrc) {
  const int h = blockIdx.y;
  const int lane = threadIdx.x & 63;
  const int wv = rfl(threadIdx.x >> 6);
  float w[64];
#pragma unroll
  for (int f = 0; f < 64; ++f) w[f] = Wsrc[f * 640 + h * 64 + lane];
  const int nw = gridDim.x * 4;
  for (int n = blockIdx.x * 4 + wv; n < NN; n += nw) {
    const float* xr = x + (size_t)n * 64;
    float a0 = 0, a1 = 0, a2 = 0, a3 = 0;
#pragma unroll
    for (int f = 0; f < 64; f += 4) {
      a0 = fmaf(xr[f], w[f], a0);
      a1 = fmaf(xr[f + 1], w[f + 1], a1);
      a2 = fmaf(xr[f + 2], w[f + 2], a2);
      a3 = fmaf(xr[f + 3], w[f + 3], a3);
    }
    xsrc[(size_t)n * 640 + h * 64 + lane] = (a0 + a1) + (a2 + a3);
  }
}

// ---------------------------------------------------------------------------
// eaQ = ea_sum@Wek, eaK = ea_sum@Weq, eaV = ea_sum@Wev   (naming per reference!)
__global__ __launch_bounds__(256) void k_eaqkv(const float* __restrict__ ea_sum,
                                               const float* __restrict__ Wek,
                                               const float* __restrict__ Weq,
                                               const float* __restrict__ Wev,
                                               float* __restrict__ eaQ,
                                               float* __restrict__ eaK,
                                               float* __restrict__ eaV) {
  const int lane = threadIdx.x & 63;
  const int wv = rfl(threadIdx.x >> 6);
  float wq[64], wk[64], wvv[64];
#pragma unroll
  for (int f = 0; f < 64; ++f) {
    wq[f] = Wek[f * 64 + lane];
    wk[f] = Weq[f * 64 + lane];
    wvv[f] = Wev[f * 64 + lane];
  }
  const int nw = gridDim.x * 4;
  for (int n = blockIdx.x * 4 + wv; n < NN; n += nw) {
    const float* r = ea_sum + (size_t)n * 64;
    float q0 = 0, q1 = 0, k0 = 0, k1 = 0, v0 = 0, v1 = 0;
#pragma unroll
    for (int f = 0; f < 64; f += 2) {
      q0 = fmaf(r[f], wq[f], q0);
      q1 = fmaf(r[f + 1], wq[f + 1], q1);
      k0 = fmaf(r[f], wk[f], k0);
      k1 = fmaf(r[f + 1], wk[f + 1], k1);
      v0 = fmaf(r[f], wvv[f], v0);
      v1 = fmaf(r[f + 1], wvv[f + 1], v1);
    }
    eaQ[(size_t)n * 64 + lane] = q0 + q1;
    eaK[(size_t)n * 64 + lane] = k0 + k1;
    eaV[(size_t)n * 64 + lane] = v0 + v1;
  }
}

// ---------------------------------------------------------------------------
// qk[n,h] = dot(Q_s, K_s)/8
__global__ __launch_bounds__(256) void k_qk(const float* __restrict__ xsrc,
                                            const float* __restrict__ Wnq,
                                            const float* __restrict__ Wnk,
                                            const float* __restrict__ eaQ,
                                            const float* __restrict__ eaK,
                                            const float* __restrict__ dout,
                                            float* __restrict__ qk) {
  const int lane = threadIdx.x & 63;
  const int wv = rfl(threadIdx.x >> 6);
  float wq[64], wk[64];
#pragma unroll
  for (int f = 0; f < 64; ++f) {
    wq[f] = Wnq[f * 64 + lane];
    wk[f] = Wnk[f * 64 + lane];
  }
  const int nw = gridDim.x * 4;
  for (int r = blockIdx.x * 4 + wv; r < NN * HH; r += nw) {
    int n = r / HH;
    const float* xr = xsrc + (size_t)r * 64;
    float q0 = 0, q1 = 0, k0 = 0, k1 = 0;
#pragma unroll
    for (int f = 0; f < 64; f += 2) {
      q0 = fmaf(xr[f], wq[f], q0);
      q1 = fmaf(xr[f + 1], wq[f + 1], q1);
      k0 = fmaf(xr[f], wk[f], k0);
      k1 = fmaf(xr[f + 1], wk[f + 1], k1);
    }
    float Q = (q0 + q1) + eaQ[(size_t)n * 64 + lane];
    float K = fmaf(dout[n], k0 + k1, eaK[(size_t)n * 64 + lane]);
    float p = Q * K;
#pragma unroll
    for (int off = 32; off; off >>= 1) p += __shfl_xor(p, off, 64);
    if (lane == 0) qk[r] = p * 0.125f;
  }
}

// ---------------------------------------------------------------------------
__global__ void k_softmax(const float* __restrict__ qk, float* __restrict__ sm) {
  int n = blockIdx.x * 256 + threadIdx.x;
  if (n >= NN) return;
  float v[HH];
  float mx = -1e30f;
#pragma unroll
  for (int h = 0; h < HH; ++h) {
    v[h] = qk[n * HH + h];
    mx = fmaxf(mx, v[h]);
  }
  float s = 0;
#pragma unroll
  for (int h = 0; h < HH; ++h) {
    v[h] = expf(v[h] - mx);
    s += v[h];
  }
  float inv = 1.0f / s;
#pragma unroll
  for (int h = 0; h < HH; ++h) sm[n * HH + h] = v[h] * inv;
}

// ---------------------------------------------------------------------------
// node_update + node_out + NB (= node_update @ W4_bot)
__global__ __launch_bounds__(256) void k_update(const float* __restrict__ xsrc,
                                                const float* __restrict__ Wnv,
                                                const float* __restrict__ W4,
                                                const float* __restrict__ eaV,
                                                const float* __restrict__ dout,
                                                const float* __restrict__ sm,
                                                const float* __restrict__ bias,
                                                float* __restrict__ node_out,
                                                float* __restrict__ NB) {
  __shared__ float lds[4][64];
  const int lane = threadIdx.x & 63;
  const int wv = rfl(threadIdx.x >> 6);
  float wvv[64], w4b[64];
#pragma unroll
  for (int f = 0; f < 64; ++f) {
    wvv[f] = Wnv[f * 64 + lane];
    w4b[f] = W4[(64 + f) * 64 + lane];
  }
  const int nw = gridDim.x * 4;
  for (int r = blockIdx.x * 4 + wv; r < NN * HH; r += nw) {
    int n = r / HH;
    int h = r - n * HH;
    const float* xr = xsrc + (size_t)r * 64;
    float a0 = 0, a1 = 0, a2 = 0, a3 = 0;
#pragma unroll
    for (int f = 0; f < 64; f += 4) {
      a0 = fmaf(xr[f], wvv[f], a0);
      a1 = fmaf(xr[f + 1], wvv[f + 1], a1);
      a2 = fmaf(xr[f + 2], wvv[f + 2], a2);
      a3 = fmaf(xr[f + 3], wvv[f + 3], a3);
    }
    float V = fmaf(dout[n], (a0 + a1) + (a2 + a3), eaV[(size_t)n * 64 + lane]);
    float nu = xr[lane] * sm[r] * V;
    node_out[(size_t)r * 64 + lane] = nu + bias[h * 64 + lane];
    lds[wv][lane] = nu;
    float b0 = 0, b1 = 0, b2 = 0, b3 = 0;
#pragma unroll
    for (int k = 0; k < 64; k += 4) {
      float4 m4 = *reinterpret_cast<const float4*>(&lds[wv][k]);
      b0 = fmaf(m4.x, w4b[k], b0);
      b1 = fmaf(m4.y, w4b[k + 1], b1);
      b2 = fmaf(m4.z, w4b[k + 2], b2);
      b3 = fmaf(m4.w, w4b[k + 3], b3);
    }
    NB[(size_t)r * 64 + lane] = (b0 + b1) + (b2 + b3);
  }
}

// ---------------------------------------------------------------------------
// Edge MLP v4: WAVE per edge, lane = output channel c, heads looped inside.
// Same as v3 but the two matvec accumulations use 4 independent chains
// (breaks the 64-long dependent fma chain -> 4x ILP on the VALU).
__global__ __launch_bounds__(256) void k_edge3(const int* __restrict__ ei,
                                               const float* __restrict__ ea_g,
                                               const float* __restrict__ NB,
                                               const float* __restrict__ A_ws,
                                               const float* __restrict__ W5,
                                               const float* __restrict__ Cg,
                                               const float* __restrict__ Cb,
                                               const float* __restrict__ g1v,
                                               const float* __restrict__ g2v,
                                               const float* __restrict__ b2v,
                                               float* __restrict__ edge_out) {
  __shared__ float bcast[WPB][64];  // one 256B broadcast slot per wave
  const int lane = threadIdx.x & 63;
  const int wv = rfl(threadIdx.x >> 6);
  float w5[64];
#pragma unroll
  for (int f = 0; f < 64; ++f) w5[f] = W5[f * 64 + lane];
  const float cg_c = Cg[lane];
  const float cb_c = Cb[lane];
  const float g1_c = g1v[lane];
  const float g2_c = g2v[lane];
  const float b2_c = b2v[lane];

  const int e = blockIdx.x * WPB + wv;  // grid is exact: EE/WPB blocks
  const int src = ei[e];
  const float ea_c = ea_g[(size_t)e * 64 + lane];
  const float A_c = A_ws[(size_t)e * 64 + lane];
  const float* nbp = NB + (size_t)src * 640 + lane;
  float* bc = &bcast[wv][0];

  float acc = 0.f;
  float nbv = nbp[0];
#pragma unroll 1
  for (int h = 0; h < HH; ++h) {
    float nbn = (h < HH - 1) ? nbp[(h + 1) * 64] : 0.f;  // prefetch next head
    // ---- matvec1: broadcast m = relu(A+nb); u = ea + sum_f m_f*W5[f][c]
    float m = fmaxf(A_c + nbv, 0.f);
    bc[lane] = m;
    float u0 = ea_c, u1 = 0.f, u2 = 0.f, u3 = 0.f;
#pragma unroll
    for (int q = 0; q < 16; ++q) {
      float4 mv = *reinterpret_cast<const float4*>(bc + 4 * q);  // uniform addr: broadcast
      u0 = fmaf(mv.x, w5[4 * q], u0);
      u1 = fmaf(mv.y, w5[4 * q + 1], u1);
      u2 = fmaf(mv.z, w5[4 * q + 2], u2);
      u3 = fmaf(mv.w, w5[4 * q + 3], u3);
    }
    float u = (u0 + u1) + (u2 + u3);
    // ---- LN1 stats across lanes (biased var, eps=0)
    float s = u, s2 = u * u;
#pragma unroll
    for (int off = 1; off < 64; off <<= 1) {
      s += __shfl_xor(s, off, 64);
      s2 += __shfl_xor(s2, off, 64);
    }
    float mu1 = s * 0.015625f;
    float rs1 = rsqrtf(s2 * 0.015625f - mu1 * mu1);
    // ---- matvec2: broadcast u*g1; ep = sum_f (u_f g1_f)*W5[f][c]
    bc[lane] = u * g1_c;
    float p0 = 0.f, p1 = 0.f, p2 = 0.f, p3 = 0.f;
#pragma unroll
    for (int q = 0; q < 16; ++q) {
      float4 mv = *reinterpret_cast<const float4*>(bc + 4 * q);
      p0 = fmaf(mv.x, w5[4 * q], p0);
      p1 = fmaf(mv.y, w5[4 * q + 1], p1);
      p2 = fmaf(mv.z, w5[4 * q + 2], p2);
      p3 = fmaf(mv.w, w5[4 * q + 3], p3);
    }
    float ep = (p0 + p1) + (p2 + p3);
    float base = fmaf(-mu1 * rs1, cg_c, ea_c + cb_c);
    ep = fmaf(rs1, ep, base);
    // ---- LN2 stats
    float t = ep, t2 = ep * ep;
#pragma unroll
    for (int off = 1; off < 64; off <<= 1) {
      t += __shfl_xor(t, off, 64);
      t2 += __shfl_xor(t2, off, 64);
    }
    float mu2 = t * 0.015625f;
    float rs2 = rsqrtf(t2 * 0.015625f - mu2 * mu2);
    acc += fmaf((ep - mu2) * rs2, g2_c, b2_c);
    nbv = nbn;
  }
  edge_out[(size_t)e * 64 + lane] = acc * 0.1f;
}

// ---------------------------------------------------------------------------
extern "C" void kernel_launch(void* const* d_in, const int* in_sizes, int n_in,
                              void* d_out, int out_size, void* d_ws, size_t ws_size,
                              hipStream_t stream) {
  const float* x = (const float*)d_in[0];
  const int* ei = (const int*)d_in[1];
  const float* edge_attr = (const float*)d_in[2];
  const float* W_src = (const float*)d_in[3];
  const float* Wnq = (const float*)d_in[4];
  const float* Wnk = (const float*)d_in[5];
  const float* Wnv = (const float*)d_in[6];
  const float* Weq = (const float*)d_in[7];
  const float* Wev = (const float*)d_in[8];
  const float* Wek = (const float*)d_in[9];
  const float* W4 = (const float*)d_in[10];
  const float* W5 = (const float*)d_in[11];
  const float* g1 = (const float*)d_in[12];
  const float* b1 = (const float*)d_in[13];
  const float* g2 = (const float*)d_in[14];
  const float* b2 = (const float*)d_in[15];
  const float* bias = (const float*)d_in[16];
  (void)in_sizes; (void)n_in; (void)out_size; (void)ws_size;

  float* ws = (float*)d_ws;
  float* deg = ws;
  float* dout = ws + NN;
  float* sum_in = ws + 2 * NN;
  float* sum_src = ws + 66 * NN;
  float* ea_sum = ws + 130 * NN;
  float* eaQ = ws + 194 * NN;
  float* eaK = ws + 258 * NN;
  float* eaV = ws + 322 * NN;
  float* xsrc = ws + 386 * NN;
  float* NB = ws + 1026 * NN;
  float* qk = ws + 1666 * NN;
  float* sm = ws + 1676 * NN;
  float* A = ws + 1686 * NN;
  float* Cg = ws + 1686 * NN + 64 * EE;
  float* Cb = Cg + 64;

  float* node_out = (float*)d_out;
  float* edge_out = (float*)d_out + (size_t)NN * 640;

  k_init<<<1024, 256, 0, stream>>>(ws);
  k_prep<<<1, 64, 0, stream>>>(W5, g1, b1, Cg, Cb);
  k_scatter<<<EE * 64 / 256, 256, 0, stream>>>(ei, edge_attr, deg, dout, sum_in, sum_src);
  k_easum<<<NN * 64 / 256, 256, 0, stream>>>(deg, sum_in, sum_src, ea_sum);
  k_rowmm<<<512, 256, 0, stream>>>(edge_attr, W4, A, EE);  // A = ea @ W4_top
  k_xsrc<<<dim3(256, 10), 256, 0, stream>>>(x, W_src, xsrc);
  k_eaqkv<<<128, 256, 0, stream>>>(ea_sum, Wek, Weq, Wev, eaQ, eaK, eaV);
  k_qk<<<512, 256, 0, stream>>>(xsrc, Wnq, Wnk, eaQ, eaK, dout, qk);
  k_softmax<<<(NN + 255) / 256, 256, 0, stream>>>(qk, sm);
  k_update<<<512, 256, 0, stream>>>(xsrc, Wnv, W4, eaV, dout, sm, bias, node_out, NB);
  k_edge3<<<EE / WPB, WPB * 64, 0, stream>>>(ei, edge_attr, NB, A, W5, Cg, Cb, g1, g2, b2,
                                             edge_out);
}

// Round 6
// 550.483 us; speedup vs baseline: 1.1049x; 1.1049x over previous
//
#include <hip/hip_runtime.h>
#include <cstdint>
#include <cstddef>

#define NN 8000
#define EE 64000
#define HH 10
#define WPB 4  // waves (edges) per k_edge4 block

// ---------------- ws layout (float offsets) ----------------
// deg      : 0          (NN)
// dout     : NN         (NN)      (init 1.0, accumulates outdeg -> outdeg+1)
// sum_in   : 2*NN       (64*NN)
// sum_src  : 66*NN      (64*NN)
// W5T      : 130*NN     (4096)    (= W5 transposed, [c][f])
// eaQ      : 194*NN     (64*NN)   (= ea_sum @ Wek)
// eaK      : 258*NN     (64*NN)   (= ea_sum @ Weq)
// eaV      : 322*NN     (64*NN)   (= ea_sum @ Wev)
// xsrc     : 386*NN     (640*NN)
// NB       : 1026*NN    (640*NN)  (= node_update @ W4_bot)
// qk       : 1666*NN    (10*NN)
// sm       : 1676*NN    (10*NN)
// A        : 1686*NN    (64*EE)   (= edge_attr @ W4_top)
// Cg       : 1686*NN+64*EE  (64)  (= g1^T @ W5)
// Cb       : +64            (64)  (= b1^T @ W5)

__device__ __forceinline__ int rfl(int v) { return __builtin_amdgcn_readfirstlane(v); }

// ---------------------------------------------------------------------------
__global__ void k_init(float* __restrict__ ws) {
  int t = blockIdx.x * 256 + threadIdx.x;
  int stride = gridDim.x * 256;
  for (int i = t; i < 130 * NN; i += stride)
    ws[i] = (i >= NN && i < 2 * NN) ? 1.0f : 0.0f;
}

// ---------------------------------------------------------------------------
__global__ void k_scatter(const int* __restrict__ ei, const float* __restrict__ ea,
                          float* __restrict__ deg, float* __restrict__ dout,
                          float* __restrict__ sum_in, float* __restrict__ sum_src) {
  int t = blockIdx.x * 256 + threadIdx.x;
  if (t >= EE * 64) return;
  int e = t >> 6, f = t & 63;
  int s = ei[e];
  int d = ei[EE + e];
  float v = ea[t];
  atomicAdd(&sum_in[d * 64 + f], v);
  atomicAdd(&sum_src[s * 64 + f], v);
  if (f == 0) {
    atomicAdd(&deg[d], 1.0f);
    atomicAdd(&dout[s], 1.0f);
  }
}

// ---------------------------------------------------------------------------
// Cg[c] = sum_f g1[f]W5[f][c]; Cb[c] = sum_f b1[f]W5[f][c]; W5T[c][f] = W5[f][c]
__global__ void k_prep(const float* __restrict__ W5, const float* __restrict__ g1,
                       const float* __restrict__ b1, float* __restrict__ Cg,
                       float* __restrict__ Cb, float* __restrict__ W5T) {
  int c = threadIdx.x;  // 64 threads
  float cg = 0.f, cb = 0.f;
  for (int f = 0; f < 64; ++f) {
    float w = W5[f * 64 + c];
    W5T[c * 64 + f] = w;
    cg = fmaf(g1[f], w, cg);
    cb = fmaf(b1[f], w, cb);
  }
  Cg[c] = cg;
  Cb[c] = cb;
}

// ---------------------------------------------------------------------------
// Row template: out[r][c] = sum_f in[r][f] * W[f][c], weights-in-VGPR.
__global__ __launch_bounds__(256) void k_rowmm(const float* __restrict__ in,
                                               const float* __restrict__ W,
                                               float* __restrict__ out, int rows) {
  const int lane = threadIdx.x & 63;
  const int wv = rfl(threadIdx.x >> 6);
  float w[64];
#pragma unroll
  for (int f = 0; f < 64; ++f) w[f] = W[f * 64 + lane];
  const int nw = gridDim.x * 4;
  for (int r = blockIdx.x * 4 + wv; r < rows; r += nw) {
    const float* xr = in + (size_t)r * 64;
    float a0 = 0, a1 = 0, a2 = 0, a3 = 0;
#pragma unroll
    for (int f = 0; f < 64; f += 4) {
      a0 = fmaf(xr[f], w[f], a0);
      a1 = fmaf(xr[f + 1], w[f + 1], a1);
      a2 = fmaf(xr[f + 2], w[f + 2], a2);
      a3 = fmaf(xr[f + 3], w[f + 3], a3);
    }
    out[(size_t)r * 64 + lane] = (a0 + a1) + (a2 + a3);
  }
}

// ---------------------------------------------------------------------------
// xsrc[n, h*64+c] = sum_f x[n][f] * Wsrc[f][h*64+c]; gridDim.y = h
__global__ __launch_bounds__(256) void k_xsrc(const float* __restrict__ x,
                                              const float* __restrict__ Wsrc,
                                              float* __restrict__ xsrc) {
  const int h = blockIdx.y;
  const int lane = threadIdx.x & 63;
  const int wv = rfl(threadIdx.x >> 6);
  float w[64];
#pragma unroll
  for (int f = 0; f < 64; ++f) w[f] = Wsrc[f * 640 + h * 64 + lane];
  const int nw = gridDim.x * 4;
  for (int n = blockIdx.x * 4 + wv; n < NN; n += nw) {
    const float* xr = x + (size_t)n * 64;
    float a0 = 0, a1 = 0, a2 = 0, a3 = 0;
#pragma unroll
    for (int f = 0; f < 64; f += 4) {
      a0 = fmaf(xr[f], w[f], a0);
      a1 = fmaf(xr[f + 1], w[f + 1], a1);
      a2 = fmaf(xr[f + 2], w[f + 2], a2);
      a3 = fmaf(xr[f + 3], w[f + 3], a3);
    }
    xsrc[(size_t)n * 640 + h * 64 + lane] = (a0 + a1) + (a2 + a3);
  }
}

// ---------------------------------------------------------------------------
// Fused ea_sum + projections: row = sum_src[n] + sum_in[n]/max(deg,1);
// eaQ = row@Wek, eaK = row@Weq, eaV = row@Wev   (naming per reference!)
__global__ __launch_bounds__(256) void k_eaqkv(const float* __restrict__ deg,
                                               const float* __restrict__ sum_in,
                                               const float* __restrict__ sum_src,
                                               const float* __restrict__ Wek,
                                               const float* __restrict__ Weq,
                                               const float* __restrict__ Wev,
                                               float* __restrict__ eaQ,
                                               float* __restrict__ eaK,
                                               float* __restrict__ eaV) {
  const int lane = threadIdx.x & 63;
  const int wv = rfl(threadIdx.x >> 6);
  float wq[64], wk[64], wvv[64];
#pragma unroll
  for (int f = 0; f < 64; ++f) {
    wq[f] = Wek[f * 64 + lane];
    wk[f] = Weq[f * 64 + lane];
    wvv[f] = Wev[f * 64 + lane];
  }
  const int nw = gridDim.x * 4;
  for (int n = blockIdx.x * 4 + wv; n < NN; n += nw) {
    const float* si = sum_in + (size_t)n * 64;
    const float* ss = sum_src + (size_t)n * 64;
    const float invd = 1.0f / fmaxf(deg[n], 1.0f);
    float q0 = 0, q1 = 0, k0 = 0, k1 = 0, v0 = 0, v1 = 0;
#pragma unroll
    for (int f = 0; f < 64; f += 2) {
      float e0 = fmaf(si[f], invd, ss[f]);
      float e1 = fmaf(si[f + 1], invd, ss[f + 1]);
      q0 = fmaf(e0, wq[f], q0);
      q1 = fmaf(e1, wq[f + 1], q1);
      k0 = fmaf(e0, wk[f], k0);
      k1 = fmaf(e1, wk[f + 1], k1);
      v0 = fmaf(e0, wvv[f], v0);
      v1 = fmaf(e1, wvv[f + 1], v1);
    }
    eaQ[(size_t)n * 64 + lane] = q0 + q1;
    eaK[(size_t)n * 64 + lane] = k0 + k1;
    eaV[(size_t)n * 64 + lane] = v0 + v1;
  }
}

// ---------------------------------------------------------------------------
// qk[n,h] = dot(Q_s, K_s)/8
__global__ __launch_bounds__(256) void k_qk(const float* __restrict__ xsrc,
                                            const float* __restrict__ Wnq,
                                            const float* __restrict__ Wnk,
                                            const float* __restrict__ eaQ,
                                            const float* __restrict__ eaK,
                                            const float* __restrict__ dout,
                                            float* __restrict__ qk) {
  const int lane = threadIdx.x & 63;
  const int wv = rfl(threadIdx.x >> 6);
  float wq[64], wk[64];
#pragma unroll
  for (int f = 0; f < 64; ++f) {
    wq[f] = Wnq[f * 64 + lane];
    wk[f] = Wnk[f * 64 + lane];
  }
  const int nw = gridDim.x * 4;
  for (int r = blockIdx.x * 4 + wv; r < NN * HH; r += nw) {
    int n = r / HH;
    const float* xr = xsrc + (size_t)r * 64;
    float q0 = 0, q1 = 0, k0 = 0, k1 = 0;
#pragma unroll
    for (int f = 0; f < 64; f += 2) {
      q0 = fmaf(xr[f], wq[f], q0);
      q1 = fmaf(xr[f + 1], wq[f + 1], q1);
      k0 = fmaf(xr[f], wk[f], k0);
      k1 = fmaf(xr[f + 1], wk[f + 1], k1);
    }
    float Q = (q0 + q1) + eaQ[(size_t)n * 64 + lane];
    float K = fmaf(dout[n], k0 + k1, eaK[(size_t)n * 64 + lane]);
    float p = Q * K;
#pragma unroll
    for (int off = 32; off; off >>= 1) p += __shfl_xor(p, off, 64);
    if (lane == 0) qk[r] = p * 0.125f;
  }
}

// ---------------------------------------------------------------------------
__global__ void k_softmax(const float* __restrict__ qk, float* __restrict__ sm) {
  int n = blockIdx.x * 256 + threadIdx.x;
  if (n >= NN) return;
  float v[HH];
  float mx = -1e30f;
#pragma unroll
  for (int h = 0; h < HH; ++h) {
    v[h] = qk[n * HH + h];
    mx = fmaxf(mx, v[h]);
  }
  float s = 0;
#pragma unroll
  for (int h = 0; h < HH; ++h) {
    v[h] = expf(v[h] - mx);
    s += v[h];
  }
  float inv = 1.0f / s;
#pragma unroll
  for (int h = 0; h < HH; ++h) sm[n * HH + h] = v[h] * inv;
}

// ---------------------------------------------------------------------------
// node_update + node_out + NB (= node_update @ W4_bot)
__global__ __launch_bounds__(256) void k_update(const float* __restrict__ xsrc,
                                                const float* __restrict__ Wnv,
                                                const float* __restrict__ W4,
                                                const float* __restrict__ eaV,
                                                const float* __restrict__ dout,
                                                const float* __restrict__ sm,
                                                const float* __restrict__ bias,
                                                float* __restrict__ node_out,
                                                float* __restrict__ NB) {
  __shared__ float lds[4][64];
  const int lane = threadIdx.x & 63;
  const int wv = rfl(threadIdx.x >> 6);
  float wvv[64], w4b[64];
#pragma unroll
  for (int f = 0; f < 64; ++f) {
    wvv[f] = Wnv[f * 64 + lane];
    w4b[f] = W4[(64 + f) * 64 + lane];
  }
  const int nw = gridDim.x * 4;
  for (int r = blockIdx.x * 4 + wv; r < NN * HH; r += nw) {
    int n = r / HH;
    int h = r - n * HH;
    const float* xr = xsrc + (size_t)r * 64;
    float a0 = 0, a1 = 0, a2 = 0, a3 = 0;
#pragma unroll
    for (int f = 0; f < 64; f += 4) {
      a0 = fmaf(xr[f], wvv[f], a0);
      a1 = fmaf(xr[f + 1], wvv[f + 1], a1);
      a2 = fmaf(xr[f + 2], wvv[f + 2], a2);
      a3 = fmaf(xr[f + 3], wvv[f + 3], a3);
    }
    float V = fmaf(dout[n], (a0 + a1) + (a2 + a3), eaV[(size_t)n * 64 + lane]);
    float nu = xr[lane] * sm[r] * V;
    node_out[(size_t)r * 64 + lane] = nu + bias[h * 64 + lane];
    lds[wv][lane] = nu;
    float b0 = 0, b1 = 0, b2 = 0, b3 = 0;
#pragma unroll
    for (int k = 0; k < 64; k += 4) {
      float4 m4 = *reinterpret_cast<const float4*>(&lds[wv][k]);
      b0 = fmaf(m4.x, w4b[k], b0);
      b1 = fmaf(m4.y, w4b[k + 1], b1);
      b2 = fmaf(m4.z, w4b[k + 2], b2);
      b3 = fmaf(m4.w, w4b[k + 3], b3);
    }
    NB[(size_t)r * 64 + lane] = (b0 + b1) + (b2 + b3);
  }
}

// ---------------------------------------------------------------------------
// Edge MLP v5: WAVE per edge, lane = output channel c, TWO heads in flight.
// Weights pinned in VGPRs via opaque asm (blocks global-load rematerialization,
// the r4/r5 stall source: VGPR_Count=48 proved w5[] was never resident).
// __launch_bounds__(256,4): cap 128 VGPR -> 4 waves/SIMD guaranteed.
__global__ __launch_bounds__(256, 4) void k_edge4(const int* __restrict__ ei,
                                                  const float* __restrict__ ea_g,
                                                  const float* __restrict__ NB,
                                                  const float* __restrict__ A_ws,
                                                  const float* __restrict__ W5T,
                                                  const float* __restrict__ Cg,
                                                  const float* __restrict__ Cb,
                                                  const float* __restrict__ g1v,
                                                  const float* __restrict__ g2v,
                                                  const float* __restrict__ b2v,
                                                  float* __restrict__ edge_out) {
  __shared__ float bcast[WPB][2][64];
  const int lane = threadIdx.x & 63;
  const int wv = rfl(threadIdx.x >> 6);
  // w5[f] = W5[f][lane], loaded coalesced from W5T[lane][f], pinned in VGPRs.
  float w5[64];
#pragma unroll
  for (int q = 0; q < 16; ++q) {
    float4 v = *reinterpret_cast<const float4*>(W5T + lane * 64 + 4 * q);
    w5[4 * q] = v.x; w5[4 * q + 1] = v.y; w5[4 * q + 2] = v.z; w5[4 * q + 3] = v.w;
  }
#pragma unroll
  for (int f = 0; f < 64; ++f) asm volatile("" : "+v"(w5[f]));
  const float cg_c = Cg[lane];
  const float cb_c = Cb[lane];
  const float g1_c = g1v[lane];
  const float g2_c = g2v[lane];
  const float b2_c = b2v[lane];

  const int e = blockIdx.x * WPB + wv;  // grid exact: EE/WPB blocks
  const int src = ei[e];
  const float ea_c = ea_g[(size_t)e * 64 + lane];
  const float A_c = A_ws[(size_t)e * 64 + lane];
  const float* nbp = NB + (size_t)src * 640 + lane;
  float* bc0 = &bcast[wv][0][0];
  float* bc1 = &bcast[wv][1][0];

  float acc = 0.f;
  float nb0 = nbp[0], nb1 = nbp[64];
#pragma unroll 1
  for (int hp = 0; hp < 5; ++hp) {
    float nbn0 = (hp < 4) ? nbp[(2 * hp + 2) * 64] : 0.f;  // prefetch next pair
    float nbn1 = (hp < 4) ? nbp[(2 * hp + 3) * 64] : 0.f;
    // ---- matvec1 (both heads): broadcast m, u = ea + sum_f m_f*W5[f][c]
    bc0[lane] = fmaxf(A_c + nb0, 0.f);
    bc1[lane] = fmaxf(A_c + nb1, 0.f);
    float ua0 = ea_c, ua1 = 0.f, ub0 = ea_c, ub1 = 0.f;
#pragma unroll
    for (int q = 0; q < 16; ++q) {
      float4 va = *reinterpret_cast<const float4*>(bc0 + 4 * q);  // uniform: broadcast
      float4 vb = *reinterpret_cast<const float4*>(bc1 + 4 * q);
      ua0 = fmaf(va.x, w5[4 * q], ua0);
      ua1 = fmaf(va.y, w5[4 * q + 1], ua1);
      ub0 = fmaf(vb.x, w5[4 * q], ub0);
      ub1 = fmaf(vb.y, w5[4 * q + 1], ub1);
      ua0 = fmaf(va.z, w5[4 * q + 2], ua0);
      ua1 = fmaf(va.w, w5[4 * q + 3], ua1);
      ub0 = fmaf(vb.z, w5[4 * q + 2], ub0);
      ub1 = fmaf(vb.w, w5[4 * q + 3], ub1);
    }
    float ua = ua0 + ua1, ub = ub0 + ub1;
    // ---- LN1 stats, both heads interleaved (4 independent butterfly streams)
    float sa = ua, sa2 = ua * ua, sb = ub, sb2 = ub * ub;
#pragma unroll
    for (int off = 1; off < 64; off <<= 1) {
      sa += __shfl_xor(sa, off, 64);
      sa2 += __shfl_xor(sa2, off, 64);
      sb += __shfl_xor(sb, off, 64);
      sb2 += __shfl_xor(sb2, off, 64);
    }
    float mua = sa * 0.015625f, mub = sb * 0.015625f;
    float rsa = rsqrtf(sa2 * 0.015625f - mua * mua);
    float rsb = rsqrtf(sb2 * 0.015625f - mub * mub);
    // ---- matvec2 (both heads): broadcast u*g1
    bc0[lane] = ua * g1_c;
    bc1[lane] = ub * g1_c;
    float pa0 = 0.f, pa1 = 0.f, pb0 = 0.f, pb1 = 0.f;
#pragma unroll
    for (int q = 0; q < 16; ++q) {
      float4 va = *reinterpret_cast<const float4*>(bc0 + 4 * q);
      float4 vb = *reinterpret_cast<const float4*>(bc1 + 4 * q);
      pa0 = fmaf(va.x, w5[4 * q], pa0);
      pa1 = fmaf(va.y, w5[4 * q + 1], pa1);
      pb0 = fmaf(vb.x, w5[4 * q], pb0);
      pb1 = fmaf(vb.y, w5[4 * q + 1], pb1);
      pa0 = fmaf(va.z, w5[4 * q + 2], pa0);
      pa1 = fmaf(va.w, w5[4 * q + 3], pa1);
      pb0 = fmaf(vb.z, w5[4 * q + 2], pb0);
      pb1 = fmaf(vb.w, w5[4 * q + 3], pb1);
    }
    float epa = fmaf(rsa, pa0 + pa1, fmaf(-mua * rsa, cg_c, ea_c + cb_c));
    float epb = fmaf(rsb, pb0 + pb1, fmaf(-mub * rsb, cg_c, ea_c + cb_c));
    // ---- LN2 stats, both heads interleaved
    float ta = epa, ta2 = epa * epa, tb = epb, tb2 = epb * epb;
#pragma unroll
    for (int off = 1; off < 64; off <<= 1) {
      ta += __shfl_xor(ta, off, 64);
      ta2 += __shfl_xor(ta2, off, 64);
      tb += __shfl_xor(tb, off, 64);
      tb2 += __shfl_xor(tb2, off, 64);
    }
    float m2a = ta * 0.015625f, m2b = tb * 0.015625f;
    float r2a = rsqrtf(ta2 * 0.015625f - m2a * m2a);
    float r2b = rsqrtf(tb2 * 0.015625f - m2b * m2b);
    acc += fmaf((epa - m2a) * r2a, g2_c, b2_c);
    acc += fmaf((epb - m2b) * r2b, g2_c, b2_c);
    nb0 = nbn0;
    nb1 = nbn1;
  }
  edge_out[(size_t)e * 64 + lane] = acc * 0.1f;
}

// ---------------------------------------------------------------------------
extern "C" void kernel_launch(void* const* d_in, const int* in_sizes, int n_in,
                              void* d_out, int out_size, void* d_ws, size_t ws_size,
                              hipStream_t stream) {
  const float* x = (const float*)d_in[0];
  const int* ei = (const int*)d_in[1];
  const float* edge_attr = (const float*)d_in[2];
  const float* W_src = (const float*)d_in[3];
  const float* Wnq = (const float*)d_in[4];
  const float* Wnk = (const float*)d_in[5];
  const float* Wnv = (const float*)d_in[6];
  const float* Weq = (const float*)d_in[7];
  const float* Wev = (const float*)d_in[8];
  const float* Wek = (const float*)d_in[9];
  const float* W4 = (const float*)d_in[10];
  const float* W5 = (const float*)d_in[11];
  const float* g1 = (const float*)d_in[12];
  const float* b1 = (const float*)d_in[13];
  const float* g2 = (const float*)d_in[14];
  const float* b2 = (const float*)d_in[15];
  const float* bias = (const float*)d_in[16];
  (void)in_sizes; (void)n_in; (void)out_size; (void)ws_size;

  float* ws = (float*)d_ws;
  float* deg = ws;
  float* dout = ws + NN;
  float* sum_in = ws + 2 * NN;
  float* sum_src = ws + 66 * NN;
  float* W5T = ws + 130 * NN;
  float* eaQ = ws + 194 * NN;
  float* eaK = ws + 258 * NN;
  float* eaV = ws + 322 * NN;
  float* xsrc = ws + 386 * NN;
  float* NB = ws + 1026 * NN;
  float* qk = ws + 1666 * NN;
  float* sm = ws + 1676 * NN;
  float* A = ws + 1686 * NN;
  float* Cg = ws + 1686 * NN + 64 * EE;
  float* Cb = Cg + 64;

  float* node_out = (float*)d_out;
  float* edge_out = (float*)d_out + (size_t)NN * 640;

  k_init<<<1024, 256, 0, stream>>>(ws);
  k_prep<<<1, 64, 0, stream>>>(W5, g1, b1, Cg, Cb, W5T);
  k_scatter<<<EE * 64 / 256, 256, 0, stream>>>(ei, edge_attr, deg, dout, sum_in, sum_src);
  k_rowmm<<<512, 256, 0, stream>>>(edge_attr, W4, A, EE);  // A = ea @ W4_top
  k_xsrc<<<dim3(256, 10), 256, 0, stream>>>(x, W_src, xsrc);
  k_eaqkv<<<128, 256, 0, stream>>>(deg, sum_in, sum_src, Wek, Weq, Wev, eaQ, eaK, eaV);
  k_qk<<<512, 256, 0, stream>>>(xsrc, Wnq, Wnk, eaQ, eaK, dout, qk);
  k_softmax<<<(NN + 255) / 256, 256, 0, stream>>>(qk, sm);
  k_update<<<512, 256, 0, stream>>>(xsrc, Wnv, W4, eaV, dout, sm, bias, node_out, NB);
  k_edge4<<<EE / WPB, WPB * 64, 0, stream>>>(ei, edge_attr, NB, A, W5T, Cg, Cb, g1, g2, b2,
                                             edge_out);
}

// Round 8
// 296.921 us; speedup vs baseline: 2.0484x; 1.8540x over previous
//
#include <hip/hip_runtime.h>
#include <cstdint>
#include <cstddef>

#define NN 8000
#define EE 64000
#define HH 10

typedef __attribute__((ext_vector_type(8))) short bf16x8;
typedef __attribute__((ext_vector_type(4))) float f32x4;
typedef __attribute__((ext_vector_type(4))) unsigned int u32x4;

__device__ __forceinline__ int rfl(int v) { return __builtin_amdgcn_readfirstlane(v); }

// ---- split 8 consecutive f32 into bf16 hi/lo fragments (truncation; residual
// captured by lo => 3-term MFMA error ~2^-16 relative)
__device__ __forceinline__ void split8(f32x4 a, f32x4 b, bf16x8& hi, bf16x8& lo) {
  unsigned int h[4], l[4];
#pragma unroll
  for (int j = 0; j < 2; ++j) {
    unsigned int b0 = __float_as_uint(a[2 * j]);
    unsigned int b1 = __float_as_uint(a[2 * j + 1]);
    h[j] = (b1 & 0xFFFF0000u) | (b0 >> 16);
    float r0 = a[2 * j] - __uint_as_float(b0 & 0xFFFF0000u);
    float r1 = a[2 * j + 1] - __uint_as_float(b1 & 0xFFFF0000u);
    l[j] = (__float_as_uint(r1) & 0xFFFF0000u) | (__float_as_uint(r0) >> 16);
  }
#pragma unroll
  for (int j = 0; j < 2; ++j) {
    unsigned int b0 = __float_as_uint(b[2 * j]);
    unsigned int b1 = __float_as_uint(b[2 * j + 1]);
    h[2 + j] = (b1 & 0xFFFF0000u) | (b0 >> 16);
    float r0 = b[2 * j] - __uint_as_float(b0 & 0xFFFF0000u);
    float r1 = b[2 * j + 1] - __uint_as_float(b1 & 0xFFFF0000u);
    l[2 + j] = (__float_as_uint(r1) & 0xFFFF0000u) | (__float_as_uint(r0) >> 16);
  }
  u32x4 uh = {h[0], h[1], h[2], h[3]};
  u32x4 ul = {l[0], l[1], l[2], l[3]};
  hi = __builtin_bit_cast(bf16x8, uh);
  lo = __builtin_bit_cast(bf16x8, ul);
}

__device__ __forceinline__ f32x4 relu4(f32x4 a, f32x4 b) {
  f32x4 o;
#pragma unroll
  for (int j = 0; j < 4; ++j) o[j] = fmaxf(a[j] + b[j], 0.f);
  return o;
}

// ---------------------------------------------------------------------------
__global__ void k_init(float* __restrict__ ws) {
  int t = blockIdx.x * 256 + threadIdx.x;
  int stride = gridDim.x * 256;
  for (int i = t; i < 130 * NN; i += stride)
    ws[i] = (i >= NN && i < 2 * NN) ? 1.0f : 0.0f;
}

// ---------------------------------------------------------------------------
__global__ void k_scatter(const int* __restrict__ ei, const float* __restrict__ ea,
                          float* __restrict__ deg, float* __restrict__ dout,
                          float* __restrict__ sum_in, float* __restrict__ sum_src) {
  int t = blockIdx.x * 256 + threadIdx.x;
  if (t >= EE * 64) return;
  int e = t >> 6, f = t & 63;
  int s = ei[e];
  int d = ei[EE + e];
  float v = ea[t];
  atomicAdd(&sum_in[d * 64 + f], v);
  atomicAdd(&sum_src[s * 64 + f], v);
  if (f == 0) {
    atomicAdd(&deg[d], 1.0f);
    atomicAdd(&dout[s], 1.0f);
  }
}

// ---------------------------------------------------------------------------
// Cg = g1^T@W5; Cb = b1^T@W5; W5Thi/W5Tlo = bf16 hi/lo of W5^T ([c][f])
__global__ void k_prep(const float* __restrict__ W5, const float* __restrict__ g1,
                       const float* __restrict__ b1, float* __restrict__ Cg,
                       float* __restrict__ Cb, unsigned short* __restrict__ W5Thi,
                       unsigned short* __restrict__ W5Tlo) {
  int c = threadIdx.x;  // 64 threads
  float cg = 0.f, cb = 0.f;
  for (int f = 0; f < 64; ++f) {
    float w = W5[f * 64 + c];
    unsigned int bits = __float_as_uint(w);
    W5Thi[c * 64 + f] = (unsigned short)(bits >> 16);
    float rest = w - __uint_as_float(bits & 0xFFFF0000u);
    W5Tlo[c * 64 + f] = (unsigned short)(__float_as_uint(rest) >> 16);
    cg = fmaf(g1[f], w, cg);
    cb = fmaf(b1[f], w, cb);
  }
  Cg[c] = cg;
  Cb[c] = cb;
}

// ---------------------------------------------------------------------------
__global__ __launch_bounds__(256) void k_rowmm(const float* __restrict__ in,
                                               const float* __restrict__ W,
                                               float* __restrict__ out, int rows) {
  const int lane = threadIdx.x & 63;
  const int wv = rfl(threadIdx.x >> 6);
  float w[64];
#pragma unroll
  for (int f = 0; f < 64; ++f) w[f] = W[f * 64 + lane];
  const int nw = gridDim.x * 4;
  for (int r = blockIdx.x * 4 + wv; r < rows; r += nw) {
    const float* xr = in + (size_t)r * 64;
    float a0 = 0, a1 = 0, a2 = 0, a3 = 0;
#pragma unroll
    for (int f = 0; f < 64; f += 4) {
      a0 = fmaf(xr[f], w[f], a0);
      a1 = fmaf(xr[f + 1], w[f + 1], a1);
      a2 = fmaf(xr[f + 2], w[f + 2], a2);
      a3 = fmaf(xr[f + 3], w[f + 3], a3);
    }
    out[(size_t)r * 64 + lane] = (a0 + a1) + (a2 + a3);
  }
}

// ---------------------------------------------------------------------------
__global__ __launch_bounds__(256) void k_xsrc(const float* __restrict__ x,
                                              const float* __restrict__ Wsrc,
                                              float* __restrict__ xsrc) {
  const int h = blockIdx.y;
  const int lane = threadIdx.x & 63;
  const int wv = rfl(threadIdx.x >> 6);
  float w[64];
#pragma unroll
  for (int f = 0; f < 64; ++f) w[f] = Wsrc[f * 640 + h * 64 + lane];
  const int nw = gridDim.x * 4;
  for (int n = blockIdx.x * 4 + wv; n < NN; n += nw) {
    const float* xr = x + (size_t)n * 64;
    float a0 = 0, a1 = 0, a2 = 0, a3 = 0;
#pragma unroll
    for (int f = 0; f < 64; f += 4) {
      a0 = fmaf(xr[f], w[f], a0);
      a1 = fmaf(xr[f + 1], w[f + 1], a1);
      a2 = fmaf(xr[f + 2], w[f + 2], a2);
      a3 = fmaf(xr[f + 3], w[f + 3], a3);
    }
    xsrc[(size_t)n * 640 + h * 64 + lane] = (a0 + a1) + (a2 + a3);
  }
}

// ---------------------------------------------------------------------------
__global__ __launch_bounds__(256) void k_eaqkv(const float* __restrict__ deg,
                                               const float* __restrict__ sum_in,
                                               const float* __restrict__ sum_src,
                                               const float* __restrict__ Wek,
                                               const float* __restrict__ Weq,
                                               const float* __restrict__ Wev,
                                               float* __restrict__ eaQ,
                                               float* __restrict__ eaK,
                                               float* __restrict__ eaV) {
  const int lane = threadIdx.x & 63;
  const int wv = rfl(threadIdx.x >> 6);
  float wq[64], wk[64], wvv[64];
#pragma unroll
  for (int f = 0; f < 64; ++f) {
    wq[f] = Wek[f * 64 + lane];
    wk[f] = Weq[f * 64 + lane];
    wvv[f] = Wev[f * 64 + lane];
  }
  const int nw = gridDim.x * 4;
  for (int n = blockIdx.x * 4 + wv; n < NN; n += nw) {
    const float* si = sum_in + (size_t)n * 64;
    const float* ss = sum_src + (size_t)n * 64;
    const float invd = 1.0f / fmaxf(deg[n], 1.0f);
    float q0 = 0, q1 = 0, k0 = 0, k1 = 0, v0 = 0, v1 = 0;
#pragma unroll
    for (int f = 0; f < 64; f += 2) {
      float e0 = fmaf(si[f], invd, ss[f]);
      float e1 = fmaf(si[f + 1], invd, ss[f + 1]);
      q0 = fmaf(e0, wq[f], q0);
      q1 = fmaf(e1, wq[f + 1], q1);
      k0 = fmaf(e0, wk[f], k0);
      k1 = fmaf(e1, wk[f + 1], k1);
      v0 = fmaf(e0, wvv[f], v0);
      v1 = fmaf(e1, wvv[f + 1], v1);
    }
    eaQ[(size_t)n * 64 + lane] = q0 + q1;
    eaK[(size_t)n * 64 + lane] = k0 + k1;
    eaV[(size_t)n * 64 + lane] = v0 + v1;
  }
}

// ---------------------------------------------------------------------------
__global__ __launch_bounds__(256) void k_qk(const float* __restrict__ xsrc,
                                            const float* __restrict__ Wnq,
                                            const float* __restrict__ Wnk,
                                            const float* __restrict__ eaQ,
                                            const float* __restrict__ eaK,
                                            const float* __restrict__ dout,
                                            float* __restrict__ qk) {
  const int lane = threadIdx.x & 63;
  const int wv = rfl(threadIdx.x >> 6);
  float wq[64], wk[64];
#pragma unroll
  for (int f = 0; f < 64; ++f) {
    wq[f] = Wnq[f * 64 + lane];
    wk[f] = Wnk[f * 64 + lane];
  }
  const int nw = gridDim.x * 4;
  for (int r = blockIdx.x * 4 + wv; r < NN * HH; r += nw) {
    int n = r / HH;
    const float* xr = xsrc + (size_t)r * 64;
    float q0 = 0, q1 = 0, k0 = 0, k1 = 0;
#pragma unroll
    for (int f = 0; f < 64; f += 2) {
      q0 = fmaf(xr[f], wq[f], q0);
      q1 = fmaf(xr[f + 1], wq[f + 1], q1);
      k0 = fmaf(xr[f], wk[f], k0);
      k1 = fmaf(xr[f + 1], wk[f + 1], k1);
    }
    float Q = (q0 + q1) + eaQ[(size_t)n * 64 + lane];
    float K = fmaf(dout[n], k0 + k1, eaK[(size_t)n * 64 + lane]);
    float p = Q * K;
#pragma unroll
    for (int off = 32; off; off >>= 1) p += __shfl_xor(p, off, 64);
    if (lane == 0) qk[r] = p * 0.125f;
  }
}

// ---------------------------------------------------------------------------
__global__ void k_softmax(const float* __restrict__ qk, float* __restrict__ sm) {
  int n = blockIdx.x * 256 + threadIdx.x;
  if (n >= NN) return;
  float v[HH];
  float mx = -1e30f;
#pragma unroll
  for (int h = 0; h < HH; ++h) {
    v[h] = qk[n * HH + h];
    mx = fmaxf(mx, v[h]);
  }
  float s = 0;
#pragma unroll
  for (int h = 0; h < HH; ++h) {
    v[h] = expf(v[h] - mx);
    s += v[h];
  }
  float inv = 1.0f / s;
#pragma unroll
  for (int h = 0; h < HH; ++h) sm[n * HH + h] = v[h] * inv;
}

// ---------------------------------------------------------------------------
__global__ __launch_bounds__(256) void k_update(const float* __restrict__ xsrc,
                                                const float* __restrict__ Wnv,
                                                const float* __restrict__ W4,
                                                const float* __restrict__ eaV,
                                                const float* __restrict__ dout,
                                                const float* __restrict__ sm,
                                                const float* __restrict__ bias,
                                                float* __restrict__ node_out,
                                                float* __restrict__ NB) {
  __shared__ float lds[4][64];
  const int lane = threadIdx.x & 63;
  const int wv = rfl(threadIdx.x >> 6);
  float wvv[64], w4b[64];
#pragma unroll
  for (int f = 0; f < 64; ++f) {
    wvv[f] = Wnv[f * 64 + lane];
    w4b[f] = W4[(64 + f) * 64 + lane];
  }
  const int nw = gridDim.x * 4;
  for (int r = blockIdx.x * 4 + wv; r < NN * HH; r += nw) {
    int n = r / HH;
    int h = r - n * HH;
    const float* xr = xsrc + (size_t)r * 64;
    float a0 = 0, a1 = 0, a2 = 0, a3 = 0;
#pragma unroll
    for (int f = 0; f < 64; f += 4) {
      a0 = fmaf(xr[f], wvv[f], a0);
      a1 = fmaf(xr[f + 1], wvv[f + 1], a1);
      a2 = fmaf(xr[f + 2], wvv[f + 2], a2);
      a3 = fmaf(xr[f + 3], wvv[f + 3], a3);
    }
    float V = fmaf(dout[n], (a0 + a1) + (a2 + a3), eaV[(size_t)n * 64 + lane]);
    float nu = xr[lane] * sm[r] * V;
    node_out[(size_t)r * 64 + lane] = nu + bias[h * 64 + lane];
    lds[wv][lane] = nu;
    float b0 = 0, b1 = 0, b2 = 0, b3 = 0;
#pragma unroll
    for (int k = 0; k < 64; k += 4) {
      float4 m4 = *reinterpret_cast<const float4*>(&lds[wv][k]);
      b0 = fmaf(m4.x, w4b[k], b0);
      b1 = fmaf(m4.y, w4b[k + 1], b1);
      b2 = fmaf(m4.z, w4b[k + 2], b2);
      b3 = fmaf(m4.w, w4b[k + 3], b3);
    }
    NB[(size_t)r * 64 + lane] = (b0 + b1) + (b2 + b3);
  }
}

// ---------------------------------------------------------------------------
// Edge MLP v7 (MFMA): wave = 16 edges, loop 10 heads. Computes transposed
// D[c][r] = sum_f W5T[c][f] * m[r][f] via mfma_f32_16x16x32_bf16, 3-term
// hi/lo split for fp32-level accuracy. A = W5^T frags (resident), B = m frags
// loaded per-lane from global. C-layout: lane(g,r) holds c=16mt+4g+reg, col r.
// r7 fix: inter-matvec exchange shuffles BOTH mt candidates and selects with
// the DESTINATION lane's hiHalf (shfl returns the source lane's evaluation;
// source g' = 2(g&1)+(i>>2) is unrelated to dest's g>=2 -> r6 wrong for g=1,2).
__global__ __launch_bounds__(256) void k_edge5(
    const int* __restrict__ ei, const float* __restrict__ ea_g,
    const float* __restrict__ NB, const float* __restrict__ AT,
    const unsigned short* __restrict__ W5Thi, const unsigned short* __restrict__ W5Tlo,
    const float* __restrict__ Cgp, const float* __restrict__ Cbp,
    const float* __restrict__ g1v, const float* __restrict__ g2v,
    const float* __restrict__ bias2, float* __restrict__ edge_out) {
  const int lane = threadIdx.x & 63;
  const int wv = rfl((int)threadIdx.x >> 6);
  const int g = lane >> 4;
  const int r = lane & 15;
  const int e = (blockIdx.x * 4 + wv) * 16 + r;
  const int src = ei[e];

  // A-operand frags: lane holds W5T[16*mt + r][32*ks + 8*g + i], i=0..7
  bf16x8 whi[4][2], wlo[4][2];
#pragma unroll
  for (int mt = 0; mt < 4; ++mt)
#pragma unroll
    for (int ks = 0; ks < 2; ++ks) {
      int off = (16 * mt + r) * 64 + 32 * ks + 8 * g;
      whi[mt][ks] = *reinterpret_cast<const bf16x8*>(W5Thi + off);
      wlo[mt][ks] = *reinterpret_cast<const bf16x8*>(W5Tlo + off);
    }

  const float* ATr = AT + (size_t)e * 64 + 8 * g;
  f32x4 at0 = *reinterpret_cast<const f32x4*>(ATr);
  f32x4 at1 = *reinterpret_cast<const f32x4*>(ATr + 4);
  f32x4 at2 = *reinterpret_cast<const f32x4*>(ATr + 32);
  f32x4 at3 = *reinterpret_cast<const f32x4*>(ATr + 36);
  const float* EAr = ea_g + (size_t)e * 64;
  const float* NBr = NB + (size_t)src * 640 + 8 * g;

  const int l0 = (((2 * g) & 3) << 4) | r;      // source lane for i<4
  const int l1 = (((2 * g + 1) & 3) << 4) | r;  // source lane for i>=4
  const bool hiHalf = (g >= 2);

  f32x4 outacc[4] = {{0, 0, 0, 0}, {0, 0, 0, 0}, {0, 0, 0, 0}, {0, 0, 0, 0}};

#pragma unroll 1
  for (int h = 0; h < HH; ++h) {
    // ---- B1 frags: m[r][f] = relu(AT[e][f] + NB[src,h][f]), f = 32ks+8g+i
    const float* nb = NBr + h * 64;
    f32x4 m0 = relu4(at0, *reinterpret_cast<const f32x4*>(nb));
    f32x4 m1 = relu4(at1, *reinterpret_cast<const f32x4*>(nb + 4));
    f32x4 m2 = relu4(at2, *reinterpret_cast<const f32x4*>(nb + 32));
    f32x4 m3 = relu4(at3, *reinterpret_cast<const f32x4*>(nb + 36));
    bf16x8 mhi0, mlo0, mhi1, mlo1;
    split8(m0, m1, mhi0, mlo0);
    split8(m2, m3, mhi1, mlo1);

    // ---- MFMA1: acc1 = ea + m @ W5 (transposed: D[c][r])
    f32x4 acc1[4];
#pragma unroll
    for (int mt = 0; mt < 4; ++mt) {
      f32x4 a = *reinterpret_cast<const f32x4*>(EAr + 16 * mt + 4 * g);
      a = __builtin_amdgcn_mfma_f32_16x16x32_bf16(whi[mt][0], mhi0, a, 0, 0, 0);
      a = __builtin_amdgcn_mfma_f32_16x16x32_bf16(whi[mt][1], mhi1, a, 0, 0, 0);
      a = __builtin_amdgcn_mfma_f32_16x16x32_bf16(whi[mt][0], mlo0, a, 0, 0, 0);
      a = __builtin_amdgcn_mfma_f32_16x16x32_bf16(whi[mt][1], mlo1, a, 0, 0, 0);
      a = __builtin_amdgcn_mfma_f32_16x16x32_bf16(wlo[mt][0], mhi0, a, 0, 0, 0);
      a = __builtin_amdgcn_mfma_f32_16x16x32_bf16(wlo[mt][1], mhi1, a, 0, 0, 0);
      acc1[mt] = a;
    }

    // ---- LN1 stats for row r (held across lanes r, r+16, r+32, r+48)
    float s = 0.f, s2 = 0.f;
#pragma unroll
    for (int mt = 0; mt < 4; ++mt)
#pragma unroll
      for (int q = 0; q < 4; ++q) {
        float v = acc1[mt][q];
        s += v;
        s2 = fmaf(v, v, s2);
      }
    s += __shfl_xor(s, 16, 64);
    s2 += __shfl_xor(s2, 16, 64);
    s += __shfl_xor(s, 32, 64);
    s2 += __shfl_xor(s2, 32, 64);
    const float mu1 = s * 0.015625f;
    const float rs1 = rsqrtf(fmaxf(s2 * 0.015625f - mu1 * mu1, 1e-30f));

    // ---- exchange to B2 frags: lane (g,r) needs u_s[r][f], f=32ks+8g+i.
    // f's channel tile mt = 2ks + (g>=2); source lane g' = 2(g&1)+(i>>2).
    // Shuffle both tiles from source, select by dest hiHalf.
    f32x4 us[4];
#pragma unroll
    for (int mt = 0; mt < 4; ++mt) {
      f32x4 gv = *reinterpret_cast<const f32x4*>(g1v + 16 * mt + 4 * g);
      us[mt] = acc1[mt] * gv * rs1;
    }
    float vv[16];
#pragma unroll
    for (int ks = 0; ks < 2; ++ks)
#pragma unroll
      for (int i = 0; i < 8; ++i) {
        const int sl = (i < 4) ? l0 : l1;
        float vlo = __shfl(us[2 * ks][i & 3], sl, 64);
        float vhi = __shfl(us[2 * ks + 1][i & 3], sl, 64);
        vv[ks * 8 + i] = hiHalf ? vhi : vlo;
      }
    f32x4 q0 = {vv[0], vv[1], vv[2], vv[3]};
    f32x4 q1 = {vv[4], vv[5], vv[6], vv[7]};
    f32x4 q2 = {vv[8], vv[9], vv[10], vv[11]};
    f32x4 q3 = {vv[12], vv[13], vv[14], vv[15]};
    bf16x8 bhi0, blo0, bhi1, blo1;
    split8(q0, q1, bhi0, blo0);
    split8(q2, q3, bhi1, blo1);

    // ---- MFMA2: acc2 = (ea + Cb - mu1*rs1*Cg) + (u*g1*rs1) @ W5
    const float m1r1 = mu1 * rs1;
    f32x4 acc2[4];
#pragma unroll
    for (int mt = 0; mt < 4; ++mt) {
      f32x4 eav = *reinterpret_cast<const f32x4*>(EAr + 16 * mt + 4 * g);
      f32x4 cbv = *reinterpret_cast<const f32x4*>(Cbp + 16 * mt + 4 * g);
      f32x4 cgv = *reinterpret_cast<const f32x4*>(Cgp + 16 * mt + 4 * g);
      f32x4 a = eav + cbv - m1r1 * cgv;
      a = __builtin_amdgcn_mfma_f32_16x16x32_bf16(whi[mt][0], bhi0, a, 0, 0, 0);
      a = __builtin_amdgcn_mfma_f32_16x16x32_bf16(whi[mt][1], bhi1, a, 0, 0, 0);
      a = __builtin_amdgcn_mfma_f32_16x16x32_bf16(whi[mt][0], blo0, a, 0, 0, 0);
      a = __builtin_amdgcn_mfma_f32_16x16x32_bf16(whi[mt][1], blo1, a, 0, 0, 0);
      a = __builtin_amdgcn_mfma_f32_16x16x32_bf16(wlo[mt][0], bhi0, a, 0, 0, 0);
      a = __builtin_amdgcn_mfma_f32_16x16x32_bf16(wlo[mt][1], bhi1, a, 0, 0, 0);
      acc2[mt] = a;
    }

    // ---- LN2 + head accumulation
    float t = 0.f, t2 = 0.f;
#pragma unroll
    for (int mt = 0; mt < 4; ++mt)
#pragma unroll
      for (int q = 0; q < 4; ++q) {
        float v = acc2[mt][q];
        t += v;
        t2 = fmaf(v, v, t2);
      }
    t += __shfl_xor(t, 16, 64);
    t2 += __shfl_xor(t2, 16, 64);
    t += __shfl_xor(t, 32, 64);
    t2 += __shfl_xor(t2, 32, 64);
    const float mu2 = t * 0.015625f;
    const float rs2 = rsqrtf(fmaxf(t2 * 0.015625f - mu2 * mu2, 1e-30f));
#pragma unroll
    for (int mt = 0; mt < 4; ++mt) {
      f32x4 g2f = *reinterpret_cast<const f32x4*>(g2v + 16 * mt + 4 * g);
      f32x4 b2f = *reinterpret_cast<const f32x4*>(bias2 + 16 * mt + 4 * g);
      outacc[mt] += (acc2[mt] - mu2) * rs2 * g2f + b2f;
    }
  }

#pragma unroll
  for (int mt = 0; mt < 4; ++mt) {
    f32x4 o = outacc[mt] * 0.1f;
    *reinterpret_cast<f32x4*>(edge_out + (size_t)e * 64 + 16 * mt + 4 * g) = o;
  }
}

// ---------------------------------------------------------------------------
extern "C" void kernel_launch(void* const* d_in, const int* in_sizes, int n_in,
                              void* d_out, int out_size, void* d_ws, size_t ws_size,
                              hipStream_t stream) {
  const float* x = (const float*)d_in[0];
  const int* ei = (const int*)d_in[1];
  const float* edge_attr = (const float*)d_in[2];
  const float* W_src = (const float*)d_in[3];
  const float* Wnq = (const float*)d_in[4];
  const float* Wnk = (const float*)d_in[5];
  const float* Wnv = (const float*)d_in[6];
  const float* Weq = (const float*)d_in[7];
  const float* Wev = (const float*)d_in[8];
  const float* Wek = (const float*)d_in[9];
  const float* W4 = (const float*)d_in[10];
  const float* W5 = (const float*)d_in[11];
  const float* g1 = (const float*)d_in[12];
  const float* b1 = (const float*)d_in[13];
  const float* g2 = (const float*)d_in[14];
  const float* b2 = (const float*)d_in[15];
  const float* bias = (const float*)d_in[16];
  (void)in_sizes; (void)n_in; (void)out_size; (void)ws_size;

  float* ws = (float*)d_ws;
  float* deg = ws;
  float* dout = ws + NN;
  float* sum_in = ws + 2 * NN;
  float* sum_src = ws + 66 * NN;
  unsigned short* W5Thi = (unsigned short*)(ws + 130 * NN);
  unsigned short* W5Tlo = W5Thi + 4096;
  float* eaQ = ws + 194 * NN;
  float* eaK = ws + 258 * NN;
  float* eaV = ws + 322 * NN;
  float* xsrc = ws + 386 * NN;
  float* NB = ws + 1026 * NN;
  float* qk = ws + 1666 * NN;
  float* sm = ws + 1676 * NN;
  float* A = ws + 1686 * NN;
  float* Cg = ws + 1686 * NN + 64 * EE;
  float* Cb = Cg + 64;

  float* node_out = (float*)d_out;
  float* edge_out = (float*)d_out + (size_t)NN * 640;

  k_init<<<1024, 256, 0, stream>>>(ws);
  k_prep<<<1, 64, 0, stream>>>(W5, g1, b1, Cg, Cb, W5Thi, W5Tlo);
  k_scatter<<<EE * 64 / 256, 256, 0, stream>>>(ei, edge_attr, deg, dout, sum_in, sum_src);
  k_rowmm<<<512, 256, 0, stream>>>(edge_attr, W4, A, EE);  // A = ea @ W4_top
  k_xsrc<<<dim3(256, 10), 256, 0, stream>>>(x, W_src, xsrc);
  k_eaqkv<<<128, 256, 0, stream>>>(deg, sum_in, sum_src, Wek, Weq, Wev, eaQ, eaK, eaV);
  k_qk<<<512, 256, 0, stream>>>(xsrc, Wnq, Wnk, eaQ, eaK, dout, qk);
  k_softmax<<<(NN + 255) / 256, 256, 0, stream>>>(qk, sm);
  k_update<<<512, 256, 0, stream>>>(xsrc, Wnv, W4, eaV, dout, sm, bias, node_out, NB);
  k_edge5<<<EE / 64, 256, 0, stream>>>(ei, edge_attr, NB, A, W5Thi, W5Tlo, Cg, Cb, g1, g2,
                                       b2, edge_out);
}